// Round 3
// baseline (456.789 us; speedup 1.0000x reference)
//
#include <hip/hip_runtime.h>
#include <math.h>

#define NE 256
#define HD 4096
#define NG 8
#define TOPKG 4
#define TOPK 8

#define BM 128
#define BN 128
#define BK 32
#define NKB (HD / BK)  // 128

typedef __attribute__((ext_vector_type(8))) short short8;
typedef __attribute__((ext_vector_type(4))) float f32x4;

typedef __attribute__((address_space(1))) const void av1_void;
typedef __attribute__((address_space(3))) void av3_void;

__device__ __forceinline__ void g2l16(const void* g, void* l) {
  __builtin_amdgcn_global_load_lds((av1_void*)g, (av3_void*)l, 16, 0, 0);
}

#define MFMA __builtin_amdgcn_mfma_f32_16x16x32_bf16

// In-row XOR swizzle (involution): byte bits[5:4] ^= row bits[2:1] (= addr bits 8:7).
// Spreads the 16 rows of a quarter-wave b128 access over all eight 16B slots
// (2-way residual sharing = free). Row index (addr>>6) untouched.
__device__ __forceinline__ unsigned swz(unsigned a) {
  return a ^ (((a >> 7) & 3u) << 4);
}

// Exact 3-way bf16 split by fp32-bit truncation: x = h + m + l + O(2^-24 x).
__device__ __forceinline__ void split3(float x, unsigned short& h, unsigned short& m,
                                       unsigned short& l) {
  unsigned bx = __float_as_uint(x);
  h = (unsigned short)(bx >> 16);
  float r = x - __uint_as_float(bx & 0xffff0000u);  // exact
  unsigned br = __float_as_uint(r);
  m = (unsigned short)(br >> 16);
  float r2 = r - __uint_as_float(br & 0xffff0000u);  // exact
  l = (unsigned short)(__float_as_uint(r2) >> 16);
}

// ---------------- W[e][k] f32 -> packed bf16 splits [kb][split][e 256][k 32] ----------------
__global__ void wsplit_kernel(const float* __restrict__ W, unsigned short* __restrict__ W3) {
  int kb = blockIdx.x;  // 0..127
  int e = threadIdx.x;  // 0..255
  const float* src = W + (size_t)e * HD + kb * BK;
#pragma unroll
  for (int g = 0; g < 4; ++g) {
    float4 x0 = *(const float4*)(src + g * 8);
    float4 x1 = *(const float4*)(src + g * 8 + 4);
    float xv[8] = {x0.x, x0.y, x0.z, x0.w, x1.x, x1.y, x1.z, x1.w};
    short8 hv, mv, lv;
#pragma unroll
    for (int j = 0; j < 8; ++j) {
      unsigned short h, m, l;
      split3(xv[j], h, m, l);
      hv[j] = (short)h; mv[j] = (short)m; lv[j] = (short)l;
    }
    size_t kbase = (size_t)kb * 3 * NE * 32;
    *(short8*)(W3 + kbase + 0 * NE * 32 + (size_t)e * 32 + g * 8) = hv;
    *(short8*)(W3 + kbase + 1 * NE * 32 + (size_t)e * 32 + g * 8) = mv;
    *(short8*)(W3 + kbase + 2 * NE * 32 + (size_t)e * 32 + g * 8) = lv;
  }
}

// ---------------- logits via split-bf16 MFMA ----------------
// Block: 128 tokens x 128 experts, 256 thr = 4 waves (2M x 2N), wave tile 64x64.
__global__ __launch_bounds__(256, 1) void logits_kernel(
    const float* __restrict__ X, const unsigned short* __restrict__ W3,
    float* __restrict__ L) {
  // per buf: A splits 3*8KB | B splits 3*8KB => 48KB; double-buffered = 96KB.
  __shared__ __align__(16) char lds[2][49152];

  const int tid = threadIdx.x;
  const int lane = tid & 63;
  const int wave = tid >> 6;           // 0..3
  const int wm = wave >> 1, wn = wave & 1;
  const int bm0 = blockIdx.x * BM;
  const int n0 = blockIdx.y * BN;

  // A staging: thread t -> row t>>1, k-half t&1 (16 floats = 64B)
  const int arow = tid >> 1;
  const int akh = tid & 1;
  const float* xptr = X + (size_t)(bm0 + arow) * HD + akh * 16;
  const unsigned aw0 = swz((unsigned)(arow * 64 + akh * 32));
  const unsigned aw1 = swz((unsigned)(arow * 64 + akh * 32 + 16));

  // fragment address components
  const int akg = lane >> 4;           // k-group 0..3 (8 bf16 = 16B)
  const int arf = wm * 64 + (lane & 15);  // A frag row, + mi*16
  const int brf = wn * 64 + (lane & 15);  // B frag col, + ni*16

  f32x4 Chh[4][4], Cmid[4][4];
  double dacc[4][4][4];
#pragma unroll
  for (int mi = 0; mi < 4; ++mi)
#pragma unroll
    for (int ni = 0; ni < 4; ++ni) {
      Chh[mi][ni] = (f32x4)(0.0f);
      Cmid[mi][ni] = (f32x4)(0.0f);
#pragma unroll
      for (int j = 0; j < 4; ++j) dacc[mi][ni][j] = 0.0;
    }

  const char* wbase = (const char*)W3;

  // B staging: per split, 8KB region staged as 2 rounds of 256thr*16B; linear
  // dest, source pre-swizzled with the same involution.
  auto stageB = [&](int kb, int buf) {
#pragma unroll
    for (int s = 0; s < 3; ++s) {
      size_t sb = (((size_t)kb * 3 + s) * 256 + n0) * 64;
#pragma unroll
      for (int r = 0; r < 2; ++r) {
        unsigned d = (unsigned)(r * 4096 + tid * 16);
        g2l16(wbase + sb + swz(d), &lds[buf][24576 + s * 8192 + d]);
      }
    }
  };

  auto convertWriteA = [&](int buf, const float* xv) {
    short8 hv0, mv0, lv0, hv1, mv1, lv1;
#pragma unroll
    for (int j = 0; j < 8; ++j) {
      unsigned short h, m, l;
      split3(xv[j], h, m, l);
      hv0[j] = (short)h; mv0[j] = (short)m; lv0[j] = (short)l;
    }
#pragma unroll
    for (int j = 0; j < 8; ++j) {
      unsigned short h, m, l;
      split3(xv[8 + j], h, m, l);
      hv1[j] = (short)h; mv1[j] = (short)m; lv1[j] = (short)l;
    }
    *(short8*)(&lds[buf][0 * 8192 + aw0]) = hv0;
    *(short8*)(&lds[buf][0 * 8192 + aw1]) = hv1;
    *(short8*)(&lds[buf][1 * 8192 + aw0]) = mv0;
    *(short8*)(&lds[buf][1 * 8192 + aw1]) = mv1;
    *(short8*)(&lds[buf][2 * 8192 + aw0]) = lv0;
    *(short8*)(&lds[buf][2 * 8192 + aw1]) = lv1;
  };

  // ---- prologue: stage kb=0 into buf0 ----
  {
    float xv[16];
    float4 x0 = *(const float4*)(xptr + 0);
    float4 x1 = *(const float4*)(xptr + 4);
    float4 x2 = *(const float4*)(xptr + 8);
    float4 x3 = *(const float4*)(xptr + 12);
    xv[0]=x0.x; xv[1]=x0.y; xv[2]=x0.z; xv[3]=x0.w;
    xv[4]=x1.x; xv[5]=x1.y; xv[6]=x1.z; xv[7]=x1.w;
    xv[8]=x2.x; xv[9]=x2.y; xv[10]=x2.z; xv[11]=x2.w;
    xv[12]=x3.x; xv[13]=x3.y; xv[14]=x3.z; xv[15]=x3.w;
    stageB(0, 0);
    convertWriteA(0, xv);
  }
  __syncthreads();

  for (int kb = 0; kb < NKB; ++kb) {
    const int buf = kb & 1;
    const bool more = (kb + 1 < NKB);
    float4 x0, x1, x2, x3;
    if (more) {
      // A global loads FIRST: the later vmcnt wait for these regs leaves the
      // 6 g2l16 (issued after) still in flight (FIFO counted-vmcnt for free).
      const float* xp = xptr + (size_t)(kb + 1) * BK;
      x0 = *(const float4*)(xp + 0);
      x1 = *(const float4*)(xp + 4);
      x2 = *(const float4*)(xp + 8);
      x3 = *(const float4*)(xp + 12);
      stageB(kb + 1, buf ^ 1);
    }

    // ---- compute on buf: A frags (12 reads), then per-ni B (3 reads) + 24 MFMA ----
    short8 af[4][3];
#pragma unroll
    for (int mi = 0; mi < 4; ++mi) {
      unsigned rb = (unsigned)((arf + mi * 16) * 64 + akg * 16);
#pragma unroll
      for (int s = 0; s < 3; ++s)
        af[mi][s] = *(const short8*)(&lds[buf][s * 8192 + swz(rb)]);
    }
    __builtin_amdgcn_s_setprio(1);
#pragma unroll
    for (int ni = 0; ni < 4; ++ni) {
      unsigned cb = (unsigned)((brf + ni * 16) * 64 + akg * 16);
      short8 bh  = *(const short8*)(&lds[buf][24576 + 0 * 8192 + swz(cb)]);
      short8 bm_ = *(const short8*)(&lds[buf][24576 + 1 * 8192 + swz(cb)]);
      short8 bl  = *(const short8*)(&lds[buf][24576 + 2 * 8192 + swz(cb)]);
#pragma unroll
      for (int mi = 0; mi < 4; ++mi) {
        Chh[mi][ni]  = MFMA(af[mi][0], bh,  Chh[mi][ni], 0, 0, 0);
        Cmid[mi][ni] = MFMA(af[mi][0], bm_, Cmid[mi][ni], 0, 0, 0);
        Cmid[mi][ni] = MFMA(af[mi][1], bh,  Cmid[mi][ni], 0, 0, 0);
        Cmid[mi][ni] = MFMA(af[mi][1], bm_, Cmid[mi][ni], 0, 0, 0);
        Cmid[mi][ni] = MFMA(af[mi][0], bl,  Cmid[mi][ni], 0, 0, 0);
        Cmid[mi][ni] = MFMA(af[mi][2], bh,  Cmid[mi][ni], 0, 0, 0);
      }
    }
    __builtin_amdgcn_s_setprio(0);

    if (more) {
      float xv[16];
      xv[0]=x0.x; xv[1]=x0.y; xv[2]=x0.z; xv[3]=x0.w;
      xv[4]=x1.x; xv[5]=x1.y; xv[6]=x1.z; xv[7]=x1.w;
      xv[8]=x2.x; xv[9]=x2.y; xv[10]=x2.z; xv[11]=x2.w;
      xv[12]=x3.x; xv[13]=x3.y; xv[14]=x3.z; xv[15]=x3.w;
      convertWriteA(buf ^ 1, xv);
    }

    // drain hh chain to fp64 every 4 K-blocks (K=128 per segment)
    if ((kb & 3) == 3) {
#pragma unroll
      for (int mi = 0; mi < 4; ++mi)
#pragma unroll
        for (int ni = 0; ni < 4; ++ni)
#pragma unroll
          for (int j = 0; j < 4; ++j) {
            dacc[mi][ni][j] += (double)Chh[mi][ni][j];
            Chh[mi][ni][j] = 0.0f;
          }
    }
    __syncthreads();
  }

  // ---- epilogue: C/D layout col=lane&15, row=(lane>>4)*4+j ----
#pragma unroll
  for (int mi = 0; mi < 4; ++mi)
#pragma unroll
    for (int ni = 0; ni < 4; ++ni) {
      int rowbase = bm0 + wm * 64 + mi * 16 + (lane >> 4) * 4;
      int col = n0 + wn * 64 + ni * 16 + (lane & 15);
#pragma unroll
      for (int j = 0; j < 4; ++j)
        L[(size_t)(rowbase + j) * NE + col] =
            (float)(dacc[mi][ni][j] + (double)Cmid[mi][ni][j]);
    }
}

// ---------------- per-token gating: one block per token (unchanged) ----------------
__global__ __launch_bounds__(256) void topk_kernel(
    const float* __restrict__ L, const float* __restrict__ bias,
    float* __restrict__ out, int T) {
  int t = blockIdx.x;
  int e = threadIdx.x;
  __shared__ double sArr[NE];
  __shared__ double gsc[NG];
  __shared__ int gsel[NG];
  __shared__ double wv[4];
  __shared__ int wi[4];
  __shared__ int selIdx[TOPK];
  __shared__ double selS[TOPK];

  float lg = L[(size_t)t * NE + e];
  double s = 1.0 / (1.0 + exp(-(double)lg));
  sArr[e] = s;
  double sc = s + (double)bias[e];

  double m1 = sc, m2 = -1e300;
#pragma unroll
  for (int off = 16; off >= 1; off >>= 1) {
    double o1 = __shfl_xor(m1, off, 32);
    double o2 = __shfl_xor(m2, off, 32);
    if (o1 > m1) { m2 = fmax(m1, o2); m1 = o1; }
    else          m2 = fmax(m2, o1);
  }
  if ((e & 31) == 0) gsc[e >> 5] = m1 + m2;
  __syncthreads();

  if (e == 0) {
    unsigned chosen = 0;
    for (int c = 0; c < TOPKG; ++c) {
      double best = -1e300; int bi = 0;
      for (int g = 0; g < NG; ++g)
        if (!((chosen >> g) & 1) && gsc[g] > best) { best = gsc[g]; bi = g; }
      chosen |= 1u << bi;
    }
    for (int g = 0; g < NG; ++g) gsel[g] = (chosen >> g) & 1;
  }
  __syncthreads();

  double msc = gsel[e >> 5] ? sc : -1e300;
  int mine = 0;
  for (int it = 0; it < TOPK; ++it) {
    double v = mine ? -1e301 : msc;
    int idx = e;
#pragma unroll
    for (int off = 32; off >= 1; off >>= 1) {
      double ov = __shfl_xor(v, off, 64);
      int oi = __shfl_xor(idx, off, 64);
      if (ov > v || (ov == v && oi < idx)) { v = ov; idx = oi; }
    }
    if ((e & 63) == 0) { wv[e >> 6] = v; wi[e >> 6] = idx; }
    __syncthreads();
    if (e == 0) {
      double bv = wv[0]; int bi = wi[0];
      for (int w = 1; w < 4; ++w)
        if (wv[w] > bv || (wv[w] == bv && wi[w] < bi)) { bv = wv[w]; bi = wi[w]; }
      selIdx[it] = bi; selS[it] = sArr[bi];
    }
    __syncthreads();
    if (e == selIdx[it]) mine = 1;
  }

  if (e < TOPK) {
    double denom = 1e-20;
#pragma unroll
    for (int j = 0; j < TOPK; ++j) denom += selS[j];
    out[(size_t)t * TOPK + e] = (float)selIdx[e];
    out[(size_t)T * TOPK + (size_t)t * TOPK + e] =
        (float)(selS[e] / denom * 2.5);
  }
}

extern "C" void kernel_launch(void* const* d_in, const int* in_sizes, int n_in,
                              void* d_out, int out_size, void* d_ws, size_t ws_size,
                              hipStream_t stream) {
  const float* X = (const float*)d_in[0];
  const float* W = (const float*)d_in[1];
  const float* bias = (const float*)d_in[2];
  float* out = (float*)d_out;
  int T = in_sizes[0] / HD;  // 16384

  unsigned short* W3 = (unsigned short*)d_ws;                       // 6 MB
  float* L = (float*)((char*)d_ws + (size_t)NKB * 3 * NE * 32 * 2); // 16 MB

  wsplit_kernel<<<NKB, 256, 0, stream>>>(W, W3);
  logits_kernel<<<dim3(T / BM, NE / BN), 256, 0, stream>>>(X, W3, L);
  topk_kernel<<<T, 256, 0, stream>>>(L, bias, out, T);
}

// Round 4
// 391.661 us; speedup vs baseline: 1.1663x; 1.1663x over previous
//
#include <hip/hip_runtime.h>
#include <math.h>

#define NE 256
#define HD 4096
#define NG 8
#define TOPKG 4
#define TOPK 8

#define BM 128
#define BN 64
#define BK 32
#define NKB (HD / BK)  // 128

typedef __attribute__((ext_vector_type(8))) short short8;
typedef __attribute__((ext_vector_type(4))) float f32x4;

typedef __attribute__((address_space(1))) const void av1_void;
typedef __attribute__((address_space(3))) void av3_void;

__device__ __forceinline__ void g2l16(const void* g, void* l) {
  __builtin_amdgcn_global_load_lds((av1_void*)g, (av3_void*)l, 16, 0, 0);
}

#define MFMA __builtin_amdgcn_mfma_f32_16x16x32_bf16

// In-row XOR swizzle (involution): byte bits[5:4] ^= row bits[2:1] (= addr bits 8:7).
// Conflict-free for quarter-wave b128 row-strided reads (verified R3: conflicts -> 0).
__device__ __forceinline__ unsigned swz(unsigned a) {
  return a ^ (((a >> 7) & 3u) << 4);
}

// Exact 3-way bf16 split by fp32-bit truncation: x = h + m + l + O(2^-22 x).
__device__ __forceinline__ void split3(float x, unsigned short& h, unsigned short& m,
                                       unsigned short& l) {
  unsigned bx = __float_as_uint(x);
  h = (unsigned short)(bx >> 16);
  float r = x - __uint_as_float(bx & 0xffff0000u);  // exact
  unsigned br = __float_as_uint(r);
  m = (unsigned short)(br >> 16);
  float r2 = r - __uint_as_float(br & 0xffff0000u);  // exact
  l = (unsigned short)(__float_as_uint(r2) >> 16);
}

// ---------------- W[e][k] f32 -> packed bf16 splits [kb][split][e 256][k 32] ----------------
__global__ void wsplit_kernel(const float* __restrict__ W, unsigned short* __restrict__ W3) {
  int kb = blockIdx.x;  // 0..127
  int e = threadIdx.x;  // 0..255
  const float* src = W + (size_t)e * HD + kb * BK;
#pragma unroll
  for (int g = 0; g < 4; ++g) {
    float4 x0 = *(const float4*)(src + g * 8);
    float4 x1 = *(const float4*)(src + g * 8 + 4);
    float xv[8] = {x0.x, x0.y, x0.z, x0.w, x1.x, x1.y, x1.z, x1.w};
    short8 hv, mv, lv;
#pragma unroll
    for (int j = 0; j < 8; ++j) {
      unsigned short h, m, l;
      split3(xv[j], h, m, l);
      hv[j] = (short)h; mv[j] = (short)m; lv[j] = (short)l;
    }
    size_t kbase = (size_t)kb * 3 * NE * 32;
    *(short8*)(W3 + kbase + 0 * NE * 32 + (size_t)e * 32 + g * 8) = hv;
    *(short8*)(W3 + kbase + 1 * NE * 32 + (size_t)e * 32 + g * 8) = mv;
    *(short8*)(W3 + kbase + 2 * NE * 32 + (size_t)e * 32 + g * 8) = lv;
  }
}

// ---------------- logits via split-bf16 MFMA ----------------
// Block: 128 tokens x 64 experts, 256 thr = 4 waves (2M x 2N), wave tile 64x32.
// LDS 72KB double-buffered -> 2 resident blocks/CU (independent barriers).
__global__ __launch_bounds__(256, 2) void logits_kernel(
    const float* __restrict__ X, const unsigned short* __restrict__ W3,
    float* __restrict__ L) {
  // per buf: A splits 3*8KB | B splits 3*4KB => 36KB; double-buffered = 72KB.
  __shared__ __align__(16) char lds[2][36864];

  const int tid = threadIdx.x;
  const int lane = tid & 63;
  const int wave = tid >> 6;           // 0..3
  const int wm = wave >> 1, wn = wave & 1;
  const int bm0 = blockIdx.y * BM;     // grid: x = n-block (fast), y = m-block
  const int n0 = blockIdx.x * BN;

  // A staging: thread t -> row t>>1, k-half t&1 (16 floats = 64B)
  const int arow = tid >> 1;
  const int akh = tid & 1;
  const float* xptr = X + (size_t)(bm0 + arow) * HD + akh * 16;
  const unsigned aw0 = swz((unsigned)(arow * 64 + akh * 32));
  const unsigned aw1 = swz((unsigned)(arow * 64 + akh * 32 + 16));

  // fragment address components
  const int akg = lane >> 4;              // k-group 0..3 (8 bf16 = 16B)
  const int arf = wm * 64 + (lane & 15);  // A frag row, + mi*16
  const int brf = wn * 32 + (lane & 15);  // B frag col, + ni*16

  f32x4 Chh[4][2], Cmid[4][2];
  double dacc[4][2][4];
#pragma unroll
  for (int mi = 0; mi < 4; ++mi)
#pragma unroll
    for (int ni = 0; ni < 2; ++ni) {
      Chh[mi][ni] = (f32x4)(0.0f);
      Cmid[mi][ni] = (f32x4)(0.0f);
#pragma unroll
      for (int j = 0; j < 4; ++j) dacc[mi][ni][j] = 0.0;
    }

  const char* wbase = (const char*)W3;

  // B staging: 4KB per split (64 experts x 64B) = one round of 256thr x 16B.
  // Linear dest, source pre-swizzled with the same involution.
  auto stageB = [&](int kb, int buf) {
#pragma unroll
    for (int s = 0; s < 3; ++s) {
      size_t sb = (((size_t)kb * 3 + s) * 256 + n0) * 64;
      unsigned d = (unsigned)(tid * 16);
      g2l16(wbase + sb + swz(d), &lds[buf][24576 + s * 4096 + d]);
    }
  };

  auto convertWriteA = [&](int buf, const float* xv) {
    short8 hv0, mv0, lv0, hv1, mv1, lv1;
#pragma unroll
    for (int j = 0; j < 8; ++j) {
      unsigned short h, m, l;
      split3(xv[j], h, m, l);
      hv0[j] = (short)h; mv0[j] = (short)m; lv0[j] = (short)l;
    }
#pragma unroll
    for (int j = 0; j < 8; ++j) {
      unsigned short h, m, l;
      split3(xv[8 + j], h, m, l);
      hv1[j] = (short)h; mv1[j] = (short)m; lv1[j] = (short)l;
    }
    *(short8*)(&lds[buf][0 * 8192 + aw0]) = hv0;
    *(short8*)(&lds[buf][0 * 8192 + aw1]) = hv1;
    *(short8*)(&lds[buf][1 * 8192 + aw0]) = mv0;
    *(short8*)(&lds[buf][1 * 8192 + aw1]) = mv1;
    *(short8*)(&lds[buf][2 * 8192 + aw0]) = lv0;
    *(short8*)(&lds[buf][2 * 8192 + aw1]) = lv1;
  };

  // ---- prologue: stage kb=0 into buf0 ----
  {
    float xv[16];
    float4 x0 = *(const float4*)(xptr + 0);
    float4 x1 = *(const float4*)(xptr + 4);
    float4 x2 = *(const float4*)(xptr + 8);
    float4 x3 = *(const float4*)(xptr + 12);
    xv[0]=x0.x; xv[1]=x0.y; xv[2]=x0.z; xv[3]=x0.w;
    xv[4]=x1.x; xv[5]=x1.y; xv[6]=x1.z; xv[7]=x1.w;
    xv[8]=x2.x; xv[9]=x2.y; xv[10]=x2.z; xv[11]=x2.w;
    xv[12]=x3.x; xv[13]=x3.y; xv[14]=x3.z; xv[15]=x3.w;
    stageB(0, 0);
    convertWriteA(0, xv);
  }
  __syncthreads();

  for (int kb = 0; kb < NKB; ++kb) {
    const int buf = kb & 1;
    const bool more = (kb + 1 < NKB);
    float4 x0, x1, x2, x3;
    if (more) {
      // A global loads FIRST: the later vmcnt wait for these regs leaves the
      // 3 g2l16 (issued after) still in flight (FIFO counted-vmcnt for free).
      const float* xp = xptr + (size_t)(kb + 1) * BK;
      x0 = *(const float4*)(xp + 0);
      x1 = *(const float4*)(xp + 4);
      x2 = *(const float4*)(xp + 8);
      x3 = *(const float4*)(xp + 12);
      stageB(kb + 1, buf ^ 1);
    }

    // ---- compute on buf: A frags (12 reads), per-ni B (3 reads) + 24 MFMA ----
    short8 af[4][3];
#pragma unroll
    for (int mi = 0; mi < 4; ++mi) {
      unsigned rb = (unsigned)((arf + mi * 16) * 64 + akg * 16);
#pragma unroll
      for (int s = 0; s < 3; ++s)
        af[mi][s] = *(const short8*)(&lds[buf][s * 8192 + swz(rb)]);
    }
    __builtin_amdgcn_s_setprio(1);
#pragma unroll
    for (int ni = 0; ni < 2; ++ni) {
      unsigned cb = (unsigned)((brf + ni * 16) * 64 + akg * 16);
      short8 bh  = *(const short8*)(&lds[buf][24576 + 0 * 4096 + swz(cb)]);
      short8 bm_ = *(const short8*)(&lds[buf][24576 + 1 * 4096 + swz(cb)]);
      short8 bl  = *(const short8*)(&lds[buf][24576 + 2 * 4096 + swz(cb)]);
#pragma unroll
      for (int mi = 0; mi < 4; ++mi) {
        Chh[mi][ni]  = MFMA(af[mi][0], bh,  Chh[mi][ni], 0, 0, 0);
        Cmid[mi][ni] = MFMA(af[mi][0], bm_, Cmid[mi][ni], 0, 0, 0);
        Cmid[mi][ni] = MFMA(af[mi][1], bh,  Cmid[mi][ni], 0, 0, 0);
        Cmid[mi][ni] = MFMA(af[mi][1], bm_, Cmid[mi][ni], 0, 0, 0);
        Cmid[mi][ni] = MFMA(af[mi][0], bl,  Cmid[mi][ni], 0, 0, 0);
        Cmid[mi][ni] = MFMA(af[mi][2], bh,  Cmid[mi][ni], 0, 0, 0);
      }
    }
    __builtin_amdgcn_s_setprio(0);

    if (more) {
      float xv[16];
      xv[0]=x0.x; xv[1]=x0.y; xv[2]=x0.z; xv[3]=x0.w;
      xv[4]=x1.x; xv[5]=x1.y; xv[6]=x1.z; xv[7]=x1.w;
      xv[8]=x2.x; xv[9]=x2.y; xv[10]=x2.z; xv[11]=x2.w;
      xv[12]=x3.x; xv[13]=x3.y; xv[14]=x3.z; xv[15]=x3.w;
      convertWriteA(buf ^ 1, xv);
    }

    // drain hh chain to fp64 every 4 K-blocks (K=128 per segment)
    if ((kb & 3) == 3) {
#pragma unroll
      for (int mi = 0; mi < 4; ++mi)
#pragma unroll
        for (int ni = 0; ni < 2; ++ni)
#pragma unroll
          for (int j = 0; j < 4; ++j) {
            dacc[mi][ni][j] += (double)Chh[mi][ni][j];
            Chh[mi][ni][j] = 0.0f;
          }
    }
    __syncthreads();
  }

  // ---- epilogue: C/D layout col=lane&15, row=(lane>>4)*4+j ----
#pragma unroll
  for (int mi = 0; mi < 4; ++mi)
#pragma unroll
    for (int ni = 0; ni < 2; ++ni) {
      int rowbase = bm0 + wm * 64 + mi * 16 + (lane >> 4) * 4;
      int col = n0 + wn * 32 + ni * 16 + (lane & 15);
#pragma unroll
      for (int j = 0; j < 4; ++j)
        L[(size_t)(rowbase + j) * NE + col] =
            (float)(dacc[mi][ni][j] + (double)Cmid[mi][ni][j]);
    }
}

// ---------------- per-token gating: one block per token (unchanged) ----------------
__global__ __launch_bounds__(256) void topk_kernel(
    const float* __restrict__ L, const float* __restrict__ bias,
    float* __restrict__ out, int T) {
  int t = blockIdx.x;
  int e = threadIdx.x;
  __shared__ double sArr[NE];
  __shared__ double gsc[NG];
  __shared__ int gsel[NG];
  __shared__ double wv[4];
  __shared__ int wi[4];
  __shared__ int selIdx[TOPK];
  __shared__ double selS[TOPK];

  float lg = L[(size_t)t * NE + e];
  double s = 1.0 / (1.0 + exp(-(double)lg));
  sArr[e] = s;
  double sc = s + (double)bias[e];

  double m1 = sc, m2 = -1e300;
#pragma unroll
  for (int off = 16; off >= 1; off >>= 1) {
    double o1 = __shfl_xor(m1, off, 32);
    double o2 = __shfl_xor(m2, off, 32);
    if (o1 > m1) { m2 = fmax(m1, o2); m1 = o1; }
    else          m2 = fmax(m2, o1);
  }
  if ((e & 31) == 0) gsc[e >> 5] = m1 + m2;
  __syncthreads();

  if (e == 0) {
    unsigned chosen = 0;
    for (int c = 0; c < TOPKG; ++c) {
      double best = -1e300; int bi = 0;
      for (int g = 0; g < NG; ++g)
        if (!((chosen >> g) & 1) && gsc[g] > best) { best = gsc[g]; bi = g; }
      chosen |= 1u << bi;
    }
    for (int g = 0; g < NG; ++g) gsel[g] = (chosen >> g) & 1;
  }
  __syncthreads();

  double msc = gsel[e >> 5] ? sc : -1e300;
  int mine = 0;
  for (int it = 0; it < TOPK; ++it) {
    double v = mine ? -1e301 : msc;
    int idx = e;
#pragma unroll
    for (int off = 32; off >= 1; off >>= 1) {
      double ov = __shfl_xor(v, off, 64);
      int oi = __shfl_xor(idx, off, 64);
      if (ov > v || (ov == v && oi < idx)) { v = ov; idx = oi; }
    }
    if ((e & 63) == 0) { wv[e >> 6] = v; wi[e >> 6] = idx; }
    __syncthreads();
    if (e == 0) {
      double bv = wv[0]; int bi = wi[0];
      for (int w = 1; w < 4; ++w)
        if (wv[w] > bv || (wv[w] == bv && wi[w] < bi)) { bv = wv[w]; bi = wi[w]; }
      selIdx[it] = bi; selS[it] = sArr[bi];
    }
    __syncthreads();
    if (e == selIdx[it]) mine = 1;
  }

  if (e < TOPK) {
    double denom = 1e-20;
#pragma unroll
    for (int j = 0; j < TOPK; ++j) denom += selS[j];
    out[(size_t)t * TOPK + e] = (float)selIdx[e];
    out[(size_t)T * TOPK + (size_t)t * TOPK + e] =
        (float)(selS[e] / denom * 2.5);
  }
}

extern "C" void kernel_launch(void* const* d_in, const int* in_sizes, int n_in,
                              void* d_out, int out_size, void* d_ws, size_t ws_size,
                              hipStream_t stream) {
  const float* X = (const float*)d_in[0];
  const float* W = (const float*)d_in[1];
  const float* bias = (const float*)d_in[2];
  float* out = (float*)d_out;
  int T = in_sizes[0] / HD;  // 16384

  unsigned short* W3 = (unsigned short*)d_ws;                       // 6 MB
  float* L = (float*)((char*)d_ws + (size_t)NKB * 3 * NE * 32 * 2); // 16 MB

  wsplit_kernel<<<NKB, 256, 0, stream>>>(W, W3);
  logits_kernel<<<dim3(NE / BN, T / BM), 256, 0, stream>>>(X, W3, L);
  topk_kernel<<<T, 256, 0, stream>>>(L, bias, out, T);
}

// Round 5
// 320.527 us; speedup vs baseline: 1.4251x; 1.2219x over previous
//
#include <hip/hip_runtime.h>
#include <math.h>

#define NE 256
#define HD 4096
#define NG 8
#define TOPKG 4
#define TOPK 8

#define BM 128
#define BN 128
#define BK 32
#define NKB (HD / BK)  // 128 total kb across full K

typedef __attribute__((ext_vector_type(8))) short short8;
typedef __attribute__((ext_vector_type(4))) float f32x4;

typedef __attribute__((address_space(1))) const void av1_void;
typedef __attribute__((address_space(3))) void av3_void;

__device__ __forceinline__ void g2l16(const void* g, void* l) {
  __builtin_amdgcn_global_load_lds((av1_void*)g, (av3_void*)l, 16, 0, 0);
}

#define MFMA __builtin_amdgcn_mfma_f32_16x16x32_bf16

// In-row XOR swizzle (involution): byte bits[5:4] ^= addr bits[8:7] (row bits 2:1).
// Verified conflict-free (R3/R4: SQ_LDS_BANK_CONFLICT == 0).
__device__ __forceinline__ unsigned swz(unsigned a) {
  return a ^ (((a >> 7) & 3u) << 4);
}

// Exact 3-way bf16 split by fp32-bit truncation: x = h + m + l + O(2^-22 x).
__device__ __forceinline__ void split3(float x, unsigned short& h, unsigned short& m,
                                       unsigned short& l) {
  unsigned bx = __float_as_uint(x);
  h = (unsigned short)(bx >> 16);
  float r = x - __uint_as_float(bx & 0xffff0000u);  // exact
  unsigned br = __float_as_uint(r);
  m = (unsigned short)(br >> 16);
  float r2 = r - __uint_as_float(br & 0xffff0000u);  // exact
  l = (unsigned short)(__float_as_uint(r2) >> 16);
}

// ---------------- W[e][k] f32 -> packed bf16 splits [kb][split][e 256][k 32] ----------------
__global__ void wsplit_kernel(const float* __restrict__ W, unsigned short* __restrict__ W3) {
  int kb = blockIdx.x;  // 0..127
  int e = threadIdx.x;  // 0..255
  const float* src = W + (size_t)e * HD + kb * BK;
#pragma unroll
  for (int g = 0; g < 4; ++g) {
    float4 x0 = *(const float4*)(src + g * 8);
    float4 x1 = *(const float4*)(src + g * 8 + 4);
    float xv[8] = {x0.x, x0.y, x0.z, x0.w, x1.x, x1.y, x1.z, x1.w};
    short8 hv, mv, lv;
#pragma unroll
    for (int j = 0; j < 8; ++j) {
      unsigned short h, m, l;
      split3(xv[j], h, m, l);
      hv[j] = (short)h; mv[j] = (short)m; lv[j] = (short)l;
    }
    size_t kbase = (size_t)kb * 3 * NE * 32;
    *(short8*)(W3 + kbase + 0 * NE * 32 + (size_t)e * 32 + g * 8) = hv;
    *(short8*)(W3 + kbase + 1 * NE * 32 + (size_t)e * 32 + g * 8) = mv;
    *(short8*)(W3 + kbase + 2 * NE * 32 + (size_t)e * 32 + g * 8) = lv;
  }
}

// ---------------- split-K logits: partial[z][t][e] over K-chunk of HD/KS ----------------
// Block: 128x128 tile, 256 thr = 4 waves (2M x 2N), wave tile 64x64.
// LDS: A single-buf 24KB + B double-buf 2x24KB = 72KB -> 2 resident blocks/CU.
// Pure fp32 MFMA accumulation (K-window <= 2048: logit err ~1e-5, partials
// summed in fp64 by topk).
template <int KS>
__global__ __launch_bounds__(256, 2) void logits_kernel(
    const float* __restrict__ X, const unsigned short* __restrict__ W3,
    float* __restrict__ Lp) {
  constexpr int KBS = NKB / KS;  // kb steps per block
  __shared__ __align__(16) char lds[24576 * 3];  // A | B0 | B1

  const int tid = threadIdx.x;
  const int lane = tid & 63;
  const int wave = tid >> 6;            // 0..3
  const int wm = wave >> 1, wn = wave & 1;

  // ---- XCD-aware remap: keep the n-pair (x=0,1) of a (y,z) panel on one XCD ----
  // dispatch d: xcd = d&7, j = d>>3; pair p = xcd*(16*KS) + (j>>1); x = j&1.
  const int d = blockIdx.x;
  const int xcd = d & 7;
  const int j = d >> 3;
  const int p = xcd * (16 * KS) + (j >> 1);
  const int nx = j & 1;
  const int z = p / 128;
  const int y = p % 128;

  const int bm0 = y * BM;
  const int n0 = nx * BN;
  const int kb0 = z * KBS;

  // A staging: thread t -> row t>>1, k-half t&1 (16 floats = 64B)
  const int arow = tid >> 1;
  const int akh = tid & 1;
  const float* xptr = X + (size_t)(bm0 + arow) * HD + akh * 16;
  const unsigned aw0 = swz((unsigned)(arow * 64 + akh * 32));
  const unsigned aw1 = swz((unsigned)(arow * 64 + akh * 32 + 16));

  // fragment address components
  const int akg = lane >> 4;               // k-group 0..3 (16B)
  const int arf = wm * 64 + (lane & 15);   // A frag row, + mi*16
  const int brf = wn * 64 + (lane & 15);   // B frag col, + ni*16

  f32x4 Chh[4][4], Cmid[4][4];
#pragma unroll
  for (int mi = 0; mi < 4; ++mi)
#pragma unroll
    for (int ni = 0; ni < 4; ++ni) {
      Chh[mi][ni] = (f32x4)(0.0f);
      Cmid[mi][ni] = (f32x4)(0.0f);
    }

  const char* wbase = (const char*)W3;

  // B staging: 24KB (3 splits x 128 experts x 64B); 2 rounds of 256thr x 16B
  // per split. Linear dest, source pre-swizzled (involution).
  auto stageB = [&](int kbg, int b) {
#pragma unroll
    for (int s = 0; s < 3; ++s) {
      size_t sb = (((size_t)kbg * 3 + s) * 256 + n0) * 64;
#pragma unroll
      for (int r = 0; r < 2; ++r) {
        unsigned dd = (unsigned)(r * 4096 + tid * 16);
        g2l16(wbase + sb + swz(dd), &lds[24576 + b * 24576 + s * 8192 + dd]);
      }
    }
  };

  auto convertWriteA = [&](const float* xv) {
    short8 hv0, mv0, lv0, hv1, mv1, lv1;
#pragma unroll
    for (int q = 0; q < 8; ++q) {
      unsigned short h, m, l;
      split3(xv[q], h, m, l);
      hv0[q] = (short)h; mv0[q] = (short)m; lv0[q] = (short)l;
    }
#pragma unroll
    for (int q = 0; q < 8; ++q) {
      unsigned short h, m, l;
      split3(xv[8 + q], h, m, l);
      hv1[q] = (short)h; mv1[q] = (short)m; lv1[q] = (short)l;
    }
    *(short8*)(&lds[0 * 8192 + aw0]) = hv0;
    *(short8*)(&lds[0 * 8192 + aw1]) = hv1;
    *(short8*)(&lds[1 * 8192 + aw0]) = mv0;
    *(short8*)(&lds[1 * 8192 + aw1]) = mv1;
    *(short8*)(&lds[2 * 8192 + aw0]) = lv0;
    *(short8*)(&lds[2 * 8192 + aw1]) = lv1;
  };

  // ---- prologue: stage kb0 (A into abuf, B into bbuf0) ----
  {
    const float* xp = xptr + (size_t)kb0 * BK;
    float4 x0 = *(const float4*)(xp + 0);
    float4 x1 = *(const float4*)(xp + 4);
    float4 x2 = *(const float4*)(xp + 8);
    float4 x3 = *(const float4*)(xp + 12);
    stageB(kb0, 0);
    float xv[16] = {x0.x, x0.y, x0.z, x0.w, x1.x, x1.y, x1.z, x1.w,
                    x2.x, x2.y, x2.z, x2.w, x3.x, x3.y, x3.z, x3.w};
    convertWriteA(xv);
  }
  __syncthreads();

  for (int kb = 0; kb < KBS; ++kb) {
    const int b = kb & 1;
    const bool more = (kb + 1 < KBS);
    float4 x0, x1, x2, x3;
    if (more) {
      // A loads FIRST, then B g2l16: the later vmcnt wait for the A regs
      // leaves the 6 g2l16 in flight (FIFO counted-vmcnt for free).
      const float* xp = xptr + (size_t)(kb0 + kb + 1) * BK;
      x0 = *(const float4*)(xp + 0);
      x1 = *(const float4*)(xp + 4);
      x2 = *(const float4*)(xp + 8);
      x3 = *(const float4*)(xp + 12);
      stageB(kb0 + kb + 1, b ^ 1);
    }

    // ---- compute: 12 A-frag reads, then per-ni 3 B reads + 24 MFMA ----
    short8 af[4][3];
#pragma unroll
    for (int mi = 0; mi < 4; ++mi) {
      unsigned rb = (unsigned)((arf + mi * 16) * 64 + akg * 16);
#pragma unroll
      for (int s = 0; s < 3; ++s)
        af[mi][s] = *(const short8*)(&lds[s * 8192 + swz(rb)]);
    }
    __builtin_amdgcn_s_setprio(1);
#pragma unroll
    for (int ni = 0; ni < 4; ++ni) {
      unsigned cb = (unsigned)((brf + ni * 16) * 64 + akg * 16);
      const char* bb = &lds[24576 + b * 24576];
      short8 bh  = *(const short8*)(&bb[0 * 8192 + swz(cb)]);
      short8 bm_ = *(const short8*)(&bb[1 * 8192 + swz(cb)]);
      short8 bl  = *(const short8*)(&bb[2 * 8192 + swz(cb)]);
#pragma unroll
      for (int mi = 0; mi < 4; ++mi) {
        Chh[mi][ni]  = MFMA(af[mi][0], bh,  Chh[mi][ni], 0, 0, 0);
        Cmid[mi][ni] = MFMA(af[mi][0], bm_, Cmid[mi][ni], 0, 0, 0);
        Cmid[mi][ni] = MFMA(af[mi][1], bh,  Cmid[mi][ni], 0, 0, 0);
        Cmid[mi][ni] = MFMA(af[mi][1], bm_, Cmid[mi][ni], 0, 0, 0);
        Cmid[mi][ni] = MFMA(af[mi][0], bl,  Cmid[mi][ni], 0, 0, 0);
        Cmid[mi][ni] = MFMA(af[mi][2], bh,  Cmid[mi][ni], 0, 0, 0);
      }
    }
    __builtin_amdgcn_s_setprio(0);

    __syncthreads();  // all waves done reading abuf (and bbuf[b])

    if (more) {
      float xv[16] = {x0.x, x0.y, x0.z, x0.w, x1.x, x1.y, x1.z, x1.w,
                      x2.x, x2.y, x2.z, x2.w, x3.x, x3.y, x3.z, x3.w};
      convertWriteA(xv);  // overwrite abuf (safe after barrier)
      __syncthreads();    // A visible + g2l16(kb+1) drained (had full compute to land)
    }
  }

  // ---- epilogue: partial = Chh + Cmid; C/D layout col=lane&15, row=(lane>>4)*4+j ----
  float* out = Lp + (size_t)z * (16384 * (size_t)NE);
#pragma unroll
  for (int mi = 0; mi < 4; ++mi)
#pragma unroll
    for (int ni = 0; ni < 4; ++ni) {
      int rowbase = bm0 + wm * 64 + mi * 16 + (lane >> 4) * 4;
      int col = n0 + wn * 64 + ni * 16 + (lane & 15);
#pragma unroll
      for (int q = 0; q < 4; ++q)
        out[(size_t)(rowbase + q) * NE + col] =
            (float)((double)Chh[mi][ni][q] + (double)Cmid[mi][ni][q]);
    }
}

// ---------------- per-token gating (sums KS partials in fp64) ----------------
__global__ __launch_bounds__(256) void topk_kernel(
    const float* __restrict__ Lp, const float* __restrict__ bias,
    float* __restrict__ out, int T, int ks) {
  int t = blockIdx.x;
  int e = threadIdx.x;
  __shared__ double sArr[NE];
  __shared__ double gsc[NG];
  __shared__ int gsel[NG];
  __shared__ double wv[4];
  __shared__ int wi[4];
  __shared__ int selIdx[TOPK];
  __shared__ double selS[TOPK];

  double lg = 0.0;
  for (int zz = 0; zz < ks; ++zz)
    lg += (double)Lp[(size_t)zz * T * NE + (size_t)t * NE + e];
  double s = 1.0 / (1.0 + exp(-lg));
  sArr[e] = s;
  double sc = s + (double)bias[e];

  double m1 = sc, m2 = -1e300;
#pragma unroll
  for (int off = 16; off >= 1; off >>= 1) {
    double o1 = __shfl_xor(m1, off, 32);
    double o2 = __shfl_xor(m2, off, 32);
    if (o1 > m1) { m2 = fmax(m1, o2); m1 = o1; }
    else          m2 = fmax(m2, o1);
  }
  if ((e & 31) == 0) gsc[e >> 5] = m1 + m2;
  __syncthreads();

  if (e == 0) {
    unsigned chosen = 0;
    for (int c = 0; c < TOPKG; ++c) {
      double best = -1e300; int bi = 0;
      for (int g = 0; g < NG; ++g)
        if (!((chosen >> g) & 1) && gsc[g] > best) { best = gsc[g]; bi = g; }
      chosen |= 1u << bi;
    }
    for (int g = 0; g < NG; ++g) gsel[g] = (chosen >> g) & 1;
  }
  __syncthreads();

  double msc = gsel[e >> 5] ? sc : -1e300;
  int mine = 0;
  for (int it = 0; it < TOPK; ++it) {
    double v = mine ? -1e301 : msc;
    int idx = e;
#pragma unroll
    for (int off = 32; off >= 1; off >>= 1) {
      double ov = __shfl_xor(v, off, 64);
      int oi = __shfl_xor(idx, off, 64);
      if (ov > v || (ov == v && oi < idx)) { v = ov; idx = oi; }
    }
    if ((e & 63) == 0) { wv[e >> 6] = v; wi[e >> 6] = idx; }
    __syncthreads();
    if (e == 0) {
      double bv = wv[0]; int bi = wi[0];
      for (int w = 1; w < 4; ++w)
        if (wv[w] > bv || (wv[w] == bv && wi[w] < bi)) { bv = wv[w]; bi = wi[w]; }
      selIdx[it] = bi; selS[it] = sArr[bi];
    }
    __syncthreads();
    if (e == selIdx[it]) mine = 1;
  }

  if (e < TOPK) {
    double denom = 1e-20;
#pragma unroll
    for (int jj = 0; jj < TOPK; ++jj) denom += selS[jj];
    out[(size_t)t * TOPK + e] = (float)selIdx[e];
    out[(size_t)T * TOPK + (size_t)t * TOPK + e] =
        (float)(selS[e] / denom * 2.5);
  }
}

extern "C" void kernel_launch(void* const* d_in, const int* in_sizes, int n_in,
                              void* d_out, int out_size, void* d_ws, size_t ws_size,
                              hipStream_t stream) {
  const float* X = (const float*)d_in[0];
  const float* W = (const float*)d_in[1];
  const float* bias = (const float*)d_in[2];
  float* out = (float*)d_out;
  int T = in_sizes[0] / HD;  // 16384

  unsigned short* W3 = (unsigned short*)d_ws;  // 6 MB
  const size_t w3b = (size_t)NKB * 3 * NE * 32 * 2;
  float* Lp = (float*)((char*)d_ws + w3b);

  const size_t need4 = w3b + 4ull * T * NE * 4;
  const int ks = (ws_size >= need4) ? 4 : 2;

  wsplit_kernel<<<NKB, 256, 0, stream>>>(W, W3);
  if (ks == 4)
    logits_kernel<4><<<256 * 4, 256, 0, stream>>>(X, W3, Lp);
  else
    logits_kernel<2><<<256 * 2, 256, 0, stream>>>(X, W3, Lp);
  topk_kernel<<<T, 256, 0, stream>>>(Lp, bias, out, T, ks);
}

// Round 6
// 199.841 us; speedup vs baseline: 2.2858x; 1.6039x over previous
//
#include <hip/hip_runtime.h>
#include <math.h>

#define NE 256
#define HD 4096
#define NG 8
#define TOPKG 4
#define TOPK 8

#define BM 128
#define BK 32
#define NKB (HD / BK)  // 128 kb across full K

typedef __attribute__((ext_vector_type(8))) short short8;
typedef __attribute__((ext_vector_type(4))) float f32x4;

typedef __attribute__((address_space(1))) const void av1_void;
typedef __attribute__((address_space(3))) void av3_void;

__device__ __forceinline__ void g2l16(const void* g, void* l) {
  __builtin_amdgcn_global_load_lds((av1_void*)g, (av3_void*)l, 16, 0, 0);
}

#define MFMA __builtin_amdgcn_mfma_f32_16x16x32_bf16

// In-row XOR swizzle (involution): byte bits[5:4] ^= addr bits[8:7].
// Verified conflict-free (R3-R5: SQ_LDS_BANK_CONFLICT == 0).
__device__ __forceinline__ unsigned swz(unsigned a) {
  return a ^ (((a >> 7) & 3u) << 4);
}

// Exact 3-way bf16 split by fp32-bit truncation.
__device__ __forceinline__ void split3(float x, unsigned short& h, unsigned short& m,
                                       unsigned short& l) {
  unsigned bx = __float_as_uint(x);
  h = (unsigned short)(bx >> 16);
  float r = x - __uint_as_float(bx & 0xffff0000u);
  unsigned br = __float_as_uint(r);
  m = (unsigned short)(br >> 16);
  float r2 = r - __uint_as_float(br & 0xffff0000u);
  l = (unsigned short)(__float_as_uint(r2) >> 16);
}

// ---------------- W[e][k] f32 -> packed bf16 splits [kb][split][e 256][k 32] ----------------
__global__ void wsplit_kernel(const float* __restrict__ W, unsigned short* __restrict__ W3) {
  int kb = blockIdx.x;
  int e = threadIdx.x;
  const float* src = W + (size_t)e * HD + kb * BK;
#pragma unroll
  for (int g = 0; g < 4; ++g) {
    float4 x0 = *(const float4*)(src + g * 8);
    float4 x1 = *(const float4*)(src + g * 8 + 4);
    float xv[8] = {x0.x, x0.y, x0.z, x0.w, x1.x, x1.y, x1.z, x1.w};
    short8 hv, mv, lv;
#pragma unroll
    for (int j = 0; j < 8; ++j) {
      unsigned short h, m, l;
      split3(xv[j], h, m, l);
      hv[j] = (short)h; mv[j] = (short)m; lv[j] = (short)l;
    }
    size_t kbase = (size_t)kb * 3 * NE * 32;
    *(short8*)(W3 + kbase + 0 * NE * 32 + (size_t)e * 32 + g * 8) = hv;
    *(short8*)(W3 + kbase + 1 * NE * 32 + (size_t)e * 32 + g * 8) = mv;
    *(short8*)(W3 + kbase + 2 * NE * 32 + (size_t)e * 32 + g * 8) = lv;
  }
}

// ---------------- split-K logits: 128 tokens x 256 experts per block ----------------
// 4 waves (2m x 2n), wave tile 64x128. Single merged fp32 acc (err ~8e-7, same
// class as R5's passing config). LDS: A 3x8KB + B 3x16KB = 72KB -> 2 blocks/CU.
template <int KS>
__global__ __launch_bounds__(256, 2) void logits_kernel(
    const float* __restrict__ X, const unsigned short* __restrict__ W3,
    float* __restrict__ Lp, int T) {
  constexpr int KBS = NKB / KS;
  __shared__ __align__(16) char lds[24576 + 49152];  // A splits | B splits

  const int tid = threadIdx.x;
  const int lane = tid & 63;
  const int wave = tid >> 6;
  const int wm = wave >> 1, wn = wave & 1;

  // z-clustered XCD remap: each XCD serves one z-chunk (W3 slab 1.5MB in its L2)
  const int per_xcd = 16 * KS;
  const int d = (blockIdx.x & 7) * per_xcd + (blockIdx.x >> 3);
  const int z = d >> 7;
  const int y = d & 127;
  const int bm0 = y * BM;
  const int kb0 = z * KBS;

  // A staging: thread t -> row t>>1, k-half t&1 (16 floats)
  const int arow = tid >> 1;
  const int akh = tid & 1;
  const float* xptr = X + (size_t)(bm0 + arow) * HD + akh * 16;
  const unsigned aw0 = swz((unsigned)(arow * 64 + akh * 32));
  const unsigned aw1 = swz((unsigned)(arow * 64 + akh * 32 + 16));

  const int akg = lane >> 4;               // k-group (16B)
  const int arf = wm * 64 + (lane & 15);   // A row, + mi*16
  const int bcf = wn * 128 + (lane & 15);  // B col, + ni*16

  f32x4 acc[4][8];
#pragma unroll
  for (int mi = 0; mi < 4; ++mi)
#pragma unroll
    for (int ni = 0; ni < 8; ++ni) acc[mi][ni] = (f32x4)(0.0f);

  const char* wbase = (const char*)W3;

  // B staging: 48KB (3 splits x 256 experts x 64B), 12 g2l16/thread.
  auto stageB = [&](int kbg) {
    const char* slab = wbase + (size_t)kbg * 49152;
#pragma unroll
    for (int s = 0; s < 3; ++s)
#pragma unroll
      for (int r = 0; r < 4; ++r) {
        unsigned dl = (unsigned)(r * 4096 + tid * 16);
        g2l16(slab + s * 16384 + swz(dl), &lds[24576 + s * 16384 + dl]);
      }
  };

  auto convA = [&](const float* xv) {
    short8 hv0, mv0, lv0, hv1, mv1, lv1;
#pragma unroll
    for (int q = 0; q < 8; ++q) {
      unsigned short h, m, l;
      split3(xv[q], h, m, l);
      hv0[q] = (short)h; mv0[q] = (short)m; lv0[q] = (short)l;
    }
#pragma unroll
    for (int q = 0; q < 8; ++q) {
      unsigned short h, m, l;
      split3(xv[8 + q], h, m, l);
      hv1[q] = (short)h; mv1[q] = (short)m; lv1[q] = (short)l;
    }
    *(short8*)(&lds[0 * 8192 + aw0]) = hv0;
    *(short8*)(&lds[0 * 8192 + aw1]) = hv1;
    *(short8*)(&lds[1 * 8192 + aw0]) = mv0;
    *(short8*)(&lds[1 * 8192 + aw1]) = mv1;
    *(short8*)(&lds[2 * 8192 + aw0]) = lv0;
    *(short8*)(&lds[2 * 8192 + aw1]) = lv1;
  };

  // ---- prologue ----
  {
    const float* xp = xptr + (size_t)kb0 * BK;
    float4 x0 = *(const float4*)(xp + 0);
    float4 x1 = *(const float4*)(xp + 4);
    float4 x2 = *(const float4*)(xp + 8);
    float4 x3 = *(const float4*)(xp + 12);
    stageB(kb0);
    float xv[16] = {x0.x, x0.y, x0.z, x0.w, x1.x, x1.y, x1.z, x1.w,
                    x2.x, x2.y, x2.z, x2.w, x3.x, x3.y, x3.z, x3.w};
    convA(xv);
  }
  __syncthreads();

  for (int kb = 0; kb < KBS; ++kb) {
    const bool more = (kb + 1 < KBS);

    short8 af[4][3];
#pragma unroll
    for (int mi = 0; mi < 4; ++mi) {
      unsigned rb = (unsigned)((arf + mi * 16) * 64 + akg * 16);
#pragma unroll
      for (int s = 0; s < 3; ++s)
        af[mi][s] = *(const short8*)(&lds[s * 8192 + swz(rb)]);
    }

    // x prefetch for kb+1 (issued before g2l16s -> convA's vmcnt wait
    // releases x while g2l16 stay in flight)
    float4 x0, x1, x2, x3;
    if (more) {
      const float* xp = xptr + (size_t)(kb0 + kb + 1) * BK;
      x0 = *(const float4*)(xp + 0);
      x1 = *(const float4*)(xp + 4);
      x2 = *(const float4*)(xp + 8);
      x3 = *(const float4*)(xp + 12);
    }

    __builtin_amdgcn_s_setprio(1);
#pragma unroll
    for (int ni = 0; ni < 8; ++ni) {
      unsigned cb = (unsigned)((bcf + ni * 16) * 64 + akg * 16);
      short8 bh  = *(const short8*)(&lds[24576 + 0 * 16384 + swz(cb)]);
      short8 bm_ = *(const short8*)(&lds[24576 + 1 * 16384 + swz(cb)]);
      short8 bl  = *(const short8*)(&lds[24576 + 2 * 16384 + swz(cb)]);
      // term-major: adjacent MFMAs hit different acc (no latency chain)
#pragma unroll
      for (int mi = 0; mi < 4; ++mi) acc[mi][ni] = MFMA(af[mi][0], bh,  acc[mi][ni], 0, 0, 0);
#pragma unroll
      for (int mi = 0; mi < 4; ++mi) acc[mi][ni] = MFMA(af[mi][0], bm_, acc[mi][ni], 0, 0, 0);
#pragma unroll
      for (int mi = 0; mi < 4; ++mi) acc[mi][ni] = MFMA(af[mi][1], bh,  acc[mi][ni], 0, 0, 0);
#pragma unroll
      for (int mi = 0; mi < 4; ++mi) acc[mi][ni] = MFMA(af[mi][1], bm_, acc[mi][ni], 0, 0, 0);
#pragma unroll
      for (int mi = 0; mi < 4; ++mi) acc[mi][ni] = MFMA(af[mi][0], bl,  acc[mi][ni], 0, 0, 0);
#pragma unroll
      for (int mi = 0; mi < 4; ++mi) acc[mi][ni] = MFMA(af[mi][2], bh,  acc[mi][ni], 0, 0, 0);
    }
    __builtin_amdgcn_s_setprio(0);

    __syncthreads();  // all waves done reading LDS

    if (more) {
      stageB(kb0 + kb + 1);  // overwrite B (safe after barrier)
      float xv[16] = {x0.x, x0.y, x0.z, x0.w, x1.x, x1.y, x1.z, x1.w,
                      x2.x, x2.y, x2.z, x2.w, x3.x, x3.y, x3.z, x3.w};
      convA(xv);             // overwrite A; waits x only (FIFO vmcnt)
      __syncthreads();       // staging visible + g2l16 drained
    }
  }

  // ---- epilogue: C/D col=lane&15, row=(lane>>4)*4+q ----
  float* outp = Lp + (size_t)z * ((size_t)T * NE);
#pragma unroll
  for (int mi = 0; mi < 4; ++mi)
#pragma unroll
    for (int ni = 0; ni < 8; ++ni) {
      int rowbase = bm0 + wm * 64 + mi * 16 + (lane >> 4) * 4;
      int col = wn * 128 + ni * 16 + (lane & 15);
#pragma unroll
      for (int q = 0; q < 4; ++q)
        outp[(size_t)(rowbase + q) * NE + col] = acc[mi][ni][q];
    }
}

// ---------------- gating: ONE WAVE PER TOKEN, zero barriers ----------------
// Lane owns experts 4l..4l+3. All selection math fp64; ties -> lower index.
__global__ __launch_bounds__(256) void topk_kernel(
    const float* __restrict__ Lp, const float* __restrict__ bias,
    float* __restrict__ out, int T, int ks) {
  const int lane = threadIdx.x & 63;
  const int t = blockIdx.x * 4 + (threadIdx.x >> 6);

  float4 bv = *(const float4*)(bias + lane * 4);
  double ba[4] = {bv.x, bv.y, bv.z, bv.w};

  double a0 = 0, a1 = 0, a2 = 0, a3 = 0;
  for (int zz = 0; zz < ks; ++zz) {
    float4 lv = *(const float4*)(Lp + (size_t)zz * T * NE + (size_t)t * NE + lane * 4);
    a0 += lv.x; a1 += lv.y; a2 += lv.z; a3 += lv.w;
  }
  double s[4] = {1.0 / (1.0 + exp(-a0)), 1.0 / (1.0 + exp(-a1)),
                 1.0 / (1.0 + exp(-a2)), 1.0 / (1.0 + exp(-a3))};
  double sc[4];
#pragma unroll
  for (int j = 0; j < 4; ++j) sc[j] = s[j] + ba[j];

  // group top-2 (group = 8 lanes = 32 experts)
  double m1 = sc[0], m2 = -1e300;
#pragma unroll
  for (int j = 1; j < 4; ++j) {
    if (sc[j] > m1) { m2 = m1; m1 = sc[j]; }
    else m2 = fmax(m2, sc[j]);
  }
#pragma unroll
  for (int off = 1; off <= 4; off <<= 1) {
    double o1 = __shfl_xor(m1, off);
    double o2 = __shfl_xor(m2, off);
    if (o1 > m1) { m2 = fmax(m1, o2); m1 = o1; }
    else m2 = fmax(m2, o1);
  }
  double gs = m1 + m2;

  // gather the 8 group sums, select top-4 groups (uniform per lane)
  double g[8];
#pragma unroll
  for (int gg = 0; gg < 8; ++gg) g[gg] = __shfl(gs, gg * 8);
  unsigned chosen = 0;
#pragma unroll
  for (int c = 0; c < TOPKG; ++c) {
    double best = -1e300; int bi = 0;
#pragma unroll
    for (int gg = 0; gg < 8; ++gg)
      if (!((chosen >> gg) & 1) && g[gg] > best) { best = g[gg]; bi = gg; }
    chosen |= 1u << bi;
  }
  const bool gsel = (chosen >> (lane >> 3)) & 1;

  double cand[4];
#pragma unroll
  for (int j = 0; j < 4; ++j) cand[j] = gsel ? sc[j] : -1e300;

  double wsel[TOPK]; int isel[TOPK];
  double denom = 1e-20;
#pragma unroll
  for (int it = 0; it < TOPK; ++it) {
    double v = cand[0]; int ji = 0;
#pragma unroll
    for (int j = 1; j < 4; ++j)
      if (cand[j] > v) { v = cand[j]; ji = j; }
    int idx = lane * 4 + ji;
#pragma unroll
    for (int off = 1; off <= 32; off <<= 1) {
      double ov = __shfl_xor(v, off);
      int oi = __shfl_xor(idx, off);
      if (ov > v || (ov == v && oi < idx)) { v = ov; idx = oi; }
    }
    // winner's sigmoid value (static selects only)
    int slot = idx & 3, owner = idx >> 2;
    double scand = s[0];
#pragma unroll
    for (int j = 1; j < 4; ++j) scand = (slot == j) ? s[j] : scand;
    double sval = __shfl(scand, owner);
    isel[it] = idx; wsel[it] = sval; denom += sval;
#pragma unroll
    for (int j = 0; j < 4; ++j)
      if (lane == owner && j == slot) cand[j] = -1e301;
  }

#pragma unroll
  for (int it = 0; it < TOPK; ++it)
    if (lane == it) {
      out[(size_t)t * TOPK + it] = (float)isel[it];
      out[(size_t)T * TOPK + (size_t)t * TOPK + it] =
          (float)(wsel[it] / denom * 2.5);
    }
}

extern "C" void kernel_launch(void* const* d_in, const int* in_sizes, int n_in,
                              void* d_out, int out_size, void* d_ws, size_t ws_size,
                              hipStream_t stream) {
  const float* X = (const float*)d_in[0];
  const float* W = (const float*)d_in[1];
  const float* bias = (const float*)d_in[2];
  float* out = (float*)d_out;
  int T = in_sizes[0] / HD;  // 16384

  unsigned short* W3 = (unsigned short*)d_ws;  // 6 MB
  const size_t w3b = (size_t)NKB * 3 * NE * 32 * 2;
  float* Lp = (float*)((char*)d_ws + w3b);

  const size_t need4 = w3b + 4ull * T * NE * 4;
  const int ks = (ws_size >= need4) ? 4 : 2;

  wsplit_kernel<<<NKB, 256, 0, stream>>>(W, W3);
  if (ks == 4)
    logits_kernel<4><<<128 * 4, 256, 0, stream>>>(X, W3, Lp, T);
  else
    logits_kernel<2><<<128 * 2, 256, 0, stream>>>(X, W3, Lp, T);
  topk_kernel<<<T / 4, 256, 0, stream>>>(Lp, bias, out, T, ks);
}

// Round 7
// 185.024 us; speedup vs baseline: 2.4688x; 1.0801x over previous
//
#include <hip/hip_runtime.h>
#include <math.h>

#define NE 256
#define HD 4096
#define TOPKG 4
#define TOPK 8

#define BM 128
#define BK 32
#define NKB 128        // kb across full K
#define KS 2
#define KBS (NKB / KS) // 64

typedef __attribute__((ext_vector_type(8))) short short8;
typedef __attribute__((ext_vector_type(4))) float f32x4;

typedef __attribute__((address_space(1))) const void av1_void;
typedef __attribute__((address_space(3))) void av3_void;

__device__ __forceinline__ void g2l16(const void* g, void* l) {
  __builtin_amdgcn_global_load_lds((av1_void*)g, (av3_void*)l, 16, 0, 0);
}

#define MFMA __builtin_amdgcn_mfma_f32_16x16x32_bf16

// In-row XOR swizzle (involution): byte bits[5:4] ^= addr bits[8:7].
// Verified conflict-free (R3-R6: SQ_LDS_BANK_CONFLICT == 0).
__device__ __forceinline__ unsigned swz(unsigned a) {
  return a ^ (((a >> 7) & 3u) << 4);
}

// Round-to-nearest-even bf16 (inputs are finite, well-scaled).
__device__ __forceinline__ unsigned short rneb(float x) {
  unsigned u = __float_as_uint(x);
  return (unsigned short)((u + 0x7fffu + ((u >> 16) & 1u)) >> 16);
}
// 2-way ROUNDED split: x = h + m + rho, |rho| <~ 2^-18|x| (vs 2^-16 truncated).
__device__ __forceinline__ void split2(float x, unsigned short& h, unsigned short& m) {
  h = rneb(x);
  float r = x - __uint_as_float(((unsigned)h) << 16);  // exact (RN to lower precision)
  m = rneb(r);
}

// ---------------- W[e][k] -> packed rounded splits [kb][2][e 256][k 32] bf16 ----------------
__global__ void wsplit_kernel(const float* __restrict__ W, unsigned short* __restrict__ W2) {
  const int kb = blockIdx.x >> 1;
  const int e = (blockIdx.x & 1) * 128 + (threadIdx.x >> 1);
  const int seg = (threadIdx.x & 1) * 16;
  const float* src = W + (size_t)e * HD + kb * BK + seg;
  float4 x0 = *(const float4*)(src + 0);
  float4 x1 = *(const float4*)(src + 4);
  float4 x2 = *(const float4*)(src + 8);
  float4 x3 = *(const float4*)(src + 12);
  float xv[16] = {x0.x, x0.y, x0.z, x0.w, x1.x, x1.y, x1.z, x1.w,
                  x2.x, x2.y, x2.z, x2.w, x3.x, x3.y, x3.z, x3.w};
  short8 hv0, hv1, mv0, mv1;
#pragma unroll
  for (int j = 0; j < 8; ++j) {
    unsigned short h, m;
    split2(xv[j], h, m);
    hv0[j] = (short)h; mv0[j] = (short)m;
  }
#pragma unroll
  for (int j = 0; j < 8; ++j) {
    unsigned short h, m;
    split2(xv[8 + j], h, m);
    hv1[j] = (short)h; mv1[j] = (short)m;
  }
  unsigned short* dh = W2 + (size_t)kb * 16384 + (size_t)e * 32 + seg;  // h split
  unsigned short* dm = dh + 8192;                                       // m split
  *(short8*)(dh + 0) = hv0;
  *(short8*)(dh + 8) = hv1;
  *(short8*)(dm + 0) = mv0;
  *(short8*)(dm + 8) = mv1;
}

// ---------------- split-K logits: 128 tokens x 256 experts, K-window 2048 ----------------
// 512 thr = 8 waves (2m x 4n), wave tile 64x64. 4 chains {ah,am}x{bh,bm} share one
// fp32 acc (logit err ~4e-6). Full dbuf (A 16KB + B 32KB)*2 = 96KB -> m97 schedule:
// stage(kb+1 -> buf^1) BEFORE compute(buf), ONE barrier/kb (drain hidden by MFMA).
__global__ __launch_bounds__(512, 2) void logits_kernel(
    const float* __restrict__ X, const unsigned short* __restrict__ W2,
    float* __restrict__ Lp, int T) {
  __shared__ __align__(16) char lds[2 * 49152];  // per buf: Ah 8K | Am 8K | Bh 16K | Bm 16K

  const int tid = threadIdx.x;
  const int lane = tid & 63;
  const int wave = tid >> 6;
  const int wm = wave >> 2, wn = wave & 3;

  const int z = blockIdx.x >> 7;   // K-chunk
  const int y = blockIdx.x & 127;  // token block
  const int bm0 = y * BM;
  const int kb0 = z * KBS;

  // A staging: thread -> row tid>>2, 8-float segment tid&3
  const int arow = tid >> 2;
  const int aseg = tid & 3;
  const float* xptr = X + (size_t)(bm0 + arow) * HD + aseg * 8;
  const unsigned aw = swz((unsigned)(arow * 64 + aseg * 16));

  // fragment address components
  const int akg = lane >> 4;
  const int arf = wm * 64 + (lane & 15);
  const int bcf = wn * 64 + (lane & 15);

  f32x4 acc[4][4];
#pragma unroll
  for (int mi = 0; mi < 4; ++mi)
#pragma unroll
    for (int ni = 0; ni < 4; ++ni) acc[mi][ni] = (f32x4)(0.0f);

  const char* wbase = (const char*)W2;

  // B staging: 32KB slab, 4 rounds of 512thr x 16B; linear dest, pre-swizzled src.
  auto stageB = [&](int kbg, int ob) {
    const char* slab = wbase + (size_t)kbg * 32768;
#pragma unroll
    for (int r = 0; r < 4; ++r) {
      unsigned dl = (unsigned)(r * 8192 + tid * 16);
      g2l16(slab + swz(dl), &lds[ob + 16384 + dl]);
    }
  };

  auto convA = [&](int ob, const float* xv) {
    short8 hv, mv;
#pragma unroll
    for (int q = 0; q < 8; ++q) {
      unsigned short h, m;
      split2(xv[q], h, m);
      hv[q] = (short)h; mv[q] = (short)m;
    }
    *(short8*)(&lds[ob + aw]) = hv;
    *(short8*)(&lds[ob + 8192 + aw]) = mv;
  };

  // ---- prologue: stage kb0 into buf0 ----
  {
    const float* xp = xptr + (size_t)kb0 * BK;
    float4 xa = *(const float4*)(xp + 0);
    float4 xb = *(const float4*)(xp + 4);
    stageB(kb0, 0);
    float xv[8] = {xa.x, xa.y, xa.z, xa.w, xb.x, xb.y, xb.z, xb.w};
    convA(0, xv);
  }
  __syncthreads();

  for (int kb = 0; kb < KBS; ++kb) {
    const int bb = (kb & 1) * 49152;
    const int ob = bb ^ 49152;
    const bool more = (kb + 1 < KBS);

    float4 xa, xb;
    if (more) {
      // x loads FIRST, g2l16 AFTER: convA's vmcnt wait for x does not drain g2l16.
      const float* xp = xptr + (size_t)(kb0 + kb + 1) * BK;
      xa = *(const float4*)(xp + 0);
      xb = *(const float4*)(xp + 4);
      stageB(kb0 + kb + 1, ob);
    }

    // ---- frags from current buf: 8 A + 8 B ds_read_b128 ----
    short8 af[2][4], bf[2][4];
#pragma unroll
    for (int mi = 0; mi < 4; ++mi) {
      unsigned rb = swz((unsigned)((arf + mi * 16) * 64 + akg * 16));
      af[0][mi] = *(const short8*)(&lds[bb + rb]);
      af[1][mi] = *(const short8*)(&lds[bb + 8192 + rb]);
    }
#pragma unroll
    for (int ni = 0; ni < 4; ++ni) {
      unsigned cb = swz((unsigned)((bcf + ni * 16) * 64 + akg * 16));
      bf[0][ni] = *(const short8*)(&lds[bb + 16384 + cb]);
      bf[1][ni] = *(const short8*)(&lds[bb + 32768 + cb]);
    }

    __builtin_amdgcn_s_setprio(1);
    // term-major: 16 independent accs between dependent reuses
#pragma unroll
    for (int mi = 0; mi < 4; ++mi)
#pragma unroll
      for (int ni = 0; ni < 4; ++ni)
        acc[mi][ni] = MFMA(af[0][mi], bf[0][ni], acc[mi][ni], 0, 0, 0);
#pragma unroll
    for (int mi = 0; mi < 4; ++mi)
#pragma unroll
      for (int ni = 0; ni < 4; ++ni)
        acc[mi][ni] = MFMA(af[0][mi], bf[1][ni], acc[mi][ni], 0, 0, 0);
#pragma unroll
    for (int mi = 0; mi < 4; ++mi)
#pragma unroll
      for (int ni = 0; ni < 4; ++ni)
        acc[mi][ni] = MFMA(af[1][mi], bf[0][ni], acc[mi][ni], 0, 0, 0);
#pragma unroll
    for (int mi = 0; mi < 4; ++mi)
#pragma unroll
      for (int ni = 0; ni < 4; ++ni)
        acc[mi][ni] = MFMA(af[1][mi], bf[1][ni], acc[mi][ni], 0, 0, 0);
    __builtin_amdgcn_s_setprio(0);

    if (more) {
      float xv[8] = {xa.x, xa.y, xa.z, xa.w, xb.x, xb.y, xb.z, xb.w};
      convA(ob, xv);
    }
    __syncthreads();  // buf^1 fully staged (g2l16 landed under MFMA); buf free
  }

  // ---- epilogue: C/D col=lane&15, row=(lane>>4)*4+q ----
  float* outp = Lp + (size_t)z * ((size_t)T * NE);
#pragma unroll
  for (int mi = 0; mi < 4; ++mi)
#pragma unroll
    for (int ni = 0; ni < 4; ++ni) {
      int rowbase = bm0 + wm * 64 + mi * 16 + (lane >> 4) * 4;
      int col = wn * 64 + ni * 16 + (lane & 15);
#pragma unroll
      for (int q = 0; q < 4; ++q)
        outp[(size_t)(rowbase + q) * NE + col] = acc[mi][ni][q];
    }
}

// ---------------- gating: one wave per token, zero barriers (R6-proven) ----------------
__global__ __launch_bounds__(256) void topk_kernel(
    const float* __restrict__ Lp, const float* __restrict__ bias,
    float* __restrict__ out, int T, int ks) {
  const int lane = threadIdx.x & 63;
  const int t = blockIdx.x * 4 + (threadIdx.x >> 6);

  float4 bv = *(const float4*)(bias + lane * 4);
  double ba[4] = {bv.x, bv.y, bv.z, bv.w};

  double a0 = 0, a1 = 0, a2 = 0, a3 = 0;
  for (int zz = 0; zz < ks; ++zz) {
    float4 lv = *(const float4*)(Lp + (size_t)zz * T * NE + (size_t)t * NE + lane * 4);
    a0 += lv.x; a1 += lv.y; a2 += lv.z; a3 += lv.w;
  }
  double s[4] = {1.0 / (1.0 + exp(-a0)), 1.0 / (1.0 + exp(-a1)),
                 1.0 / (1.0 + exp(-a2)), 1.0 / (1.0 + exp(-a3))};
  double sc[4];
#pragma unroll
  for (int j = 0; j < 4; ++j) sc[j] = s[j] + ba[j];

  // group top-2 (group = 8 lanes = 32 experts)
  double m1 = sc[0], m2 = -1e300;
#pragma unroll
  for (int j = 1; j < 4; ++j) {
    if (sc[j] > m1) { m2 = m1; m1 = sc[j]; }
    else m2 = fmax(m2, sc[j]);
  }
#pragma unroll
  for (int off = 1; off <= 4; off <<= 1) {
    double o1 = __shfl_xor(m1, off);
    double o2 = __shfl_xor(m2, off);
    if (o1 > m1) { m2 = fmax(m1, o2); m1 = o1; }
    else m2 = fmax(m2, o1);
  }
  double gs = m1 + m2;

  double g[8];
#pragma unroll
  for (int gg = 0; gg < 8; ++gg) g[gg] = __shfl(gs, gg * 8);
  unsigned chosen = 0;
#pragma unroll
  for (int c = 0; c < TOPKG; ++c) {
    double best = -1e300; int bi = 0;
#pragma unroll
    for (int gg = 0; gg < 8; ++gg)
      if (!((chosen >> gg) & 1) && g[gg] > best) { best = g[gg]; bi = gg; }
    chosen |= 1u << bi;
  }
  const bool gsel = (chosen >> (lane >> 3)) & 1;

  double cand[4];
#pragma unroll
  for (int j = 0; j < 4; ++j) cand[j] = gsel ? sc[j] : -1e300;

  double wsel[TOPK]; int isel[TOPK];
  double denom = 1e-20;
#pragma unroll
  for (int it = 0; it < TOPK; ++it) {
    double v = cand[0]; int ji = 0;
#pragma unroll
    for (int j = 1; j < 4; ++j)
      if (cand[j] > v) { v = cand[j]; ji = j; }
    int idx = lane * 4 + ji;
#pragma unroll
    for (int off = 1; off <= 32; off <<= 1) {
      double ov = __shfl_xor(v, off);
      int oi = __shfl_xor(idx, off);
      if (ov > v || (ov == v && oi < idx)) { v = ov; idx = oi; }
    }
    int slot = idx & 3, owner = idx >> 2;
    double scand = s[0];
#pragma unroll
    for (int j = 1; j < 4; ++j) scand = (slot == j) ? s[j] : scand;
    double sval = __shfl(scand, owner);
    isel[it] = idx; wsel[it] = sval; denom += sval;
#pragma unroll
    for (int j = 0; j < 4; ++j)
      if (lane == owner && j == slot) cand[j] = -1e301;
  }

#pragma unroll
  for (int it = 0; it < TOPK; ++it)
    if (lane == it) {
      out[(size_t)t * TOPK + it] = (float)isel[it];
      out[(size_t)T * TOPK + (size_t)t * TOPK + it] =
          (float)(wsel[it] / denom * 2.5);
    }
}

extern "C" void kernel_launch(void* const* d_in, const int* in_sizes, int n_in,
                              void* d_out, int out_size, void* d_ws, size_t ws_size,
                              hipStream_t stream) {
  const float* X = (const float*)d_in[0];
  const float* W = (const float*)d_in[1];
  const float* bias = (const float*)d_in[2];
  float* out = (float*)d_out;
  int T = in_sizes[0] / HD;  // 16384

  unsigned short* W2 = (unsigned short*)d_ws;                 // 4 MB
  float* Lp = (float*)((char*)d_ws + (size_t)NKB * 32768);    // 2 x 16 MB partials

  wsplit_kernel<<<2 * NKB, 256, 0, stream>>>(W, W2);
  logits_kernel<<<128 * KS, 512, 0, stream>>>(X, W2, Lp, T);
  topk_kernel<<<T / 4, 256, 0, stream>>>(Lp, bias, out, T, KS);
}